// Round 1
// baseline (367.774 us; speedup 1.0000x reference)
//
#include <hip/hip_runtime.h>

#define NN 64
#define CC 512
#define CIn 256
#define HW 48
#define LNSZ (CC * HW)   // 24576 elements per sample

// ---- workspace layout (float offsets) ----
// part: 4 * 64 * 48 * 512 = 6291456   (split-K partials, reused 3x)
// Th:   64*48*256 = 786432            layout [j*48+s][ci]
// Pp:   64*12*256 = 196608            layout [i*12+m][ci]
// D:    3072*768  = 2359296
// S:    3072
// y,u,v: 1572864 each                 layout [n][c][s]
static const size_t PART_OFF = 0;
static const size_t TH_OFF   = 6291456;
static const size_t PP_OFF   = 7077888;
static const size_t D_OFF    = 7274496;
static const size_t S_OFF    = 9633792;
static const size_t Y_OFF    = 9636864;
static const size_t U_OFF    = 11209728;
static const size_t V_OFF    = 12782592;
// total 14355456 floats = 57.4 MB

__device__ __forceinline__ float comp4(const float4& v, int d) {
  switch (d) {
    case 0: return v.x;
    case 1: return v.y;
    case 2: return v.z;
    default: return v.w;
  }
}

__device__ __forceinline__ void fma4(float4& a, float w, const float4& x) {
  a.x = fmaf(w, x.x, a.x);
  a.y = fmaf(w, x.y, a.y);
  a.z = fmaf(w, x.z, a.z);
  a.w = fmaf(w, x.w, a.w);
}

// Generic per-sample GEMM with split-K partials.
// Out[n, o, s] partial = sum_{c in chunk} W(o)[c] * In[n, c, s]
// W(o) = o < 256 ? W0 + o*CC : W1 + (o-256)*CC    (CO = 512 always)
// part layout: [ch][n][s][o]   (o contiguous -> coalesced stores & reads)
// Thread t: og = t&127, sh = t>>7; owns o in {og, og+128, og+256, og+384},
// s in [sh*24, sh*24+24). 96 accumulators, 6 ds_read_b128 per c, 96 FMA per c.
__global__ __launch_bounds__(256) void gemm_partial(
    const float* __restrict__ In, const float* __restrict__ W0,
    const float* __restrict__ W1, float* __restrict__ part) {
  const int ch = blockIdx.x;   // 0..3, c chunk of 128
  const int n  = blockIdx.y;   // 0..63
  const int t  = threadIdx.x;
  const int og = t & 127;
  const int sh = t >> 7;
  const int s0 = sh * 24;

  __shared__ __align__(16) float xs[128 * HW];  // 24 KB, [c_local][s]
  {
    const float4* src4 =
        (const float4*)(In + (size_t)n * LNSZ + (size_t)ch * 128 * HW);
    float4* xs4 = (float4*)xs;
#pragma unroll
    for (int k = 0; k < 6; ++k) xs4[t + k * 256] = src4[t + k * 256];
  }
  __syncthreads();

  const float* wrow[4];
#pragma unroll
  for (int k = 0; k < 4; ++k) {
    int o = og + 128 * k;
    wrow[k] = (o < 256 ? (W0 + (size_t)o * CC) : (W1 + (size_t)(o - 256) * CC))
              + ch * 128;
  }

  float4 acc[4][6];
#pragma unroll
  for (int k = 0; k < 4; ++k)
#pragma unroll
    for (int q = 0; q < 6; ++q) acc[k][q] = make_float4(0.f, 0.f, 0.f, 0.f);

  for (int cq = 0; cq < 32; ++cq) {
    float4 w4[4];
#pragma unroll
    for (int k = 0; k < 4; ++k) w4[k] = ((const float4*)wrow[k])[cq];
#pragma unroll
    for (int d = 0; d < 4; ++d) {
      const int c = cq * 4 + d;
      const float4* xrow = (const float4*)(xs + c * HW + s0);
      float4 xv[6];
#pragma unroll
      for (int q = 0; q < 6; ++q) xv[q] = xrow[q];
#pragma unroll
      for (int k = 0; k < 4; ++k) {
        const float w = comp4(w4[k], d);
#pragma unroll
        for (int q = 0; q < 6; ++q) fma4(acc[k][q], w, xv[q]);
      }
    }
  }

  float* pb = part + (size_t)(ch * NN + n) * (HW * CC);
#pragma unroll
  for (int k = 0; k < 4; ++k) {
    const int o = og + 128 * k;
#pragma unroll
    for (int q = 0; q < 6; ++q)
#pragma unroll
      for (int d = 0; d < 4; ++d) {
        const int s = s0 + q * 4 + d;
        pb[(size_t)s * CC + o] = comp4(acc[k][q], d);
      }
  }
}

// Th[(n*48+s)*256 + ci] = sum_ch part[ch][n][s][ci] + theta_b[ci]
__global__ __launch_bounds__(256) void reduce_theta(
    const float* __restrict__ part, const float* __restrict__ tb,
    float* __restrict__ Th) {
  int g = blockIdx.x * 256 + threadIdx.x;  // < 786432
  int ci = g & 255;
  int rest = g >> 8;        // n*48 + s
  int s = rest % HW;
  int n = rest / HW;
  float v = tb[ci];
#pragma unroll
  for (int ch = 0; ch < 4; ++ch)
    v += part[((size_t)(ch * NN + n) * HW + s) * CC + ci];
  Th[g] = v;
}

// Pp[(i*12+m)*256 + ci] = max over pooling window of (phi + phi_b)
// m = hh*2+ww; window s = 8*hh + 2*ww + {0,1,4,5}
__global__ __launch_bounds__(256) void reduce_pool_phi(
    const float* __restrict__ part, const float* __restrict__ pbias,
    float* __restrict__ Pp) {
  int g = blockIdx.x * 256 + threadIdx.x;  // < 196608
  int ci = g & 255;
  int rest = g >> 8;        // i*12 + m
  int m = rest % 12;
  int i = rest / 12;
  int sb = (m >> 1) * 8 + (m & 1) * 2;
  float bias = pbias[ci];
  float best = -3.4e38f;
  const int del[4] = {0, 1, 4, 5};
#pragma unroll
  for (int d = 0; d < 4; ++d) {
    int s = sb + del[d];
    float v = bias;
#pragma unroll
    for (int ch = 0; ch < 4; ++ch)
      v += part[((size_t)(ch * NN + i) * HW + s) * CC + 256 + ci];
    best = fmaxf(best, v);
  }
  Pp[g] = best;
}

// D[3072][768] = Th[3072][256] @ Pp[768][256]^T ; 64x64 tile, 4x4/thread
__global__ __launch_bounds__(256) void dgemm(const float* __restrict__ A,
                                             const float* __restrict__ B,
                                             float* __restrict__ D) {
  __shared__ float As[64][33];
  __shared__ float Bs[64][33];
  const int t = threadIdx.x;
  const int r0 = blockIdx.y * 64;
  const int c0 = blockIdx.x * 64;
  const int tx = t & 15, ty = t >> 4;
  float acc[4][4] = {};
  for (int k0 = 0; k0 < 256; k0 += 32) {
    __syncthreads();
#pragma unroll
    for (int l = 0; l < 2; ++l) {
      int idx = t + l * 256;          // 0..511
      int r = idx >> 3;
      int kq = (idx & 7) * 4;
      float4 av = *(const float4*)(A + (size_t)(r0 + r) * 256 + k0 + kq);
      As[r][kq] = av.x; As[r][kq + 1] = av.y;
      As[r][kq + 2] = av.z; As[r][kq + 3] = av.w;
      float4 bv = *(const float4*)(B + (size_t)(c0 + r) * 256 + k0 + kq);
      Bs[r][kq] = bv.x; Bs[r][kq + 1] = bv.y;
      Bs[r][kq + 2] = bv.z; Bs[r][kq + 3] = bv.w;
    }
    __syncthreads();
#pragma unroll
    for (int k = 0; k < 32; ++k) {
      float a[4], b[4];
#pragma unroll
      for (int d = 0; d < 4; ++d) {
        a[d] = As[ty * 4 + d][k];
        b[d] = Bs[tx * 4 + d][k];
      }
#pragma unroll
      for (int i = 0; i < 4; ++i)
#pragma unroll
        for (int j = 0; j < 4; ++j) acc[i][j] = fmaf(a[i], b[j], acc[i][j]);
    }
  }
#pragma unroll
  for (int i = 0; i < 4; ++i) {
    float4 o = make_float4(acc[i][0], acc[i][1], acc[i][2], acc[i][3]);
    *(float4*)(D + (size_t)(r0 + ty * 4 + i) * 768 + c0 + tx * 4) = o;
  }
}

// S[row] = (1/12) * sum_i max_{m<12} D[row][i*12+m] ; one wave per row
__global__ __launch_bounds__(256) void reduce_D(const float* __restrict__ D,
                                                float* __restrict__ S) {
  int w = threadIdx.x >> 6;
  int lane = threadIdx.x & 63;
  int row = blockIdx.x * 4 + w;   // < 3072
  const float* dr = D + (size_t)row * 768 + lane * 12;
  float4 a = *(const float4*)dr;
  float4 b = *(const float4*)(dr + 4);
  float4 c = *(const float4*)(dr + 8);
  float mx = a.x;
  mx = fmaxf(mx, a.y); mx = fmaxf(mx, a.z); mx = fmaxf(mx, a.w);
  mx = fmaxf(mx, b.x); mx = fmaxf(mx, b.y); mx = fmaxf(mx, b.z); mx = fmaxf(mx, b.w);
  mx = fmaxf(mx, c.x); mx = fmaxf(mx, c.y); mx = fmaxf(mx, c.z); mx = fmaxf(mx, c.w);
#pragma unroll
  for (int off = 32; off > 0; off >>= 1) mx += __shfl_down(mx, off, 64);
  if (lane == 0) S[row] = mx * (1.0f / 12.0f);
}

// y = LN1(x * (1 + S)) ; one block per sample, stats in double
__global__ __launch_bounds__(1024) void attn_ln1(
    const float* __restrict__ x, const float* __restrict__ S,
    const float* __restrict__ g, const float* __restrict__ b,
    float* __restrict__ y) {
  const int n = blockIdx.x, t = threadIdx.x;
  const float* xn = x + (size_t)n * LNSZ;
  __shared__ float sS[HW];
  if (t < HW) sS[t] = 1.0f + S[n * HW + t];
  __syncthreads();
  double sum = 0.0, sq = 0.0;
  for (int idx = t; idx < LNSZ; idx += 1024) {
    int s = idx % HW;
    float e = xn[idx] * sS[s];
    sum += e;
    sq += (double)e * e;
  }
  int lane = t & 63, w = t >> 6;
#pragma unroll
  for (int off = 32; off > 0; off >>= 1) {
    sum += __shfl_down(sum, off, 64);
    sq  += __shfl_down(sq, off, 64);
  }
  __shared__ double rs[16], rq[16];
  __shared__ float smu, srstd;
  if (lane == 0) { rs[w] = sum; rq[w] = sq; }
  __syncthreads();
  if (t == 0) {
    double S1 = 0, S2 = 0;
    for (int k = 0; k < 16; ++k) { S1 += rs[k]; S2 += rq[k]; }
    double mu = S1 / (double)LNSZ;
    double var = S2 / (double)LNSZ - mu * mu;
    smu = (float)mu;
    srstd = (float)(1.0 / sqrt(var + 1e-5));
  }
  __syncthreads();
  const float mu = smu, rstd = srstd;
  float* yn = y + (size_t)n * LNSZ;
  for (int idx = t; idx < LNSZ; idx += 1024) {
    int s = idx % HW;
    float e = xn[idx] * sS[s];
    yn[idx] = (e - mu) * rstd * g[idx] + b[idx];
  }
}

// u[n][c][s] = relu(sum_ch part[ch][n][s][c])
__global__ __launch_bounds__(256) void reduce_relu(
    const float* __restrict__ part, float* __restrict__ u) {
  int g = blockIdx.x * 256 + threadIdx.x;  // < 1572864, order (n, s, c)
  int c = g & 511;
  int rest = g >> 9;        // n*48 + s
  int s = rest % HW;
  int n = rest / HW;
  float v = 0.f;
#pragma unroll
  for (int ch = 0; ch < 4; ++ch)
    v += part[((size_t)(ch * NN + n) * HW + s) * CC + c];
  u[((size_t)n * CC + c) * HW + s] = fmaxf(v, 0.f);
}

// out = LN2(y + conv2_partials) ; v is scratch for the second pass
__global__ __launch_bounds__(1024) void final_ln2(
    const float* __restrict__ part, const float* __restrict__ y,
    const float* __restrict__ g2, const float* __restrict__ b2,
    float* __restrict__ v, float* __restrict__ out) {
  const int n = blockIdx.x, t = threadIdx.x;
  const size_t base = (size_t)n * LNSZ;
  double sum = 0.0, sq = 0.0;
  for (int q = t; q < LNSZ; q += 1024) {
    int c = q & 511;
    int s = q >> 9;
    float h = 0.f;
#pragma unroll
    for (int ch = 0; ch < 4; ++ch)
      h += part[((size_t)(ch * NN + n) * HW + s) * CC + c];
    float val = y[base + (size_t)c * HW + s] + h;
    v[base + (size_t)c * HW + s] = val;
    sum += val;
    sq += (double)val * val;
  }
  int lane = t & 63, w = t >> 6;
#pragma unroll
  for (int off = 32; off > 0; off >>= 1) {
    sum += __shfl_down(sum, off, 64);
    sq  += __shfl_down(sq, off, 64);
  }
  __shared__ double rs[16], rq[16];
  __shared__ float smu, srstd;
  if (lane == 0) { rs[w] = sum; rq[w] = sq; }
  __syncthreads();
  if (t == 0) {
    double S1 = 0, S2 = 0;
    for (int k = 0; k < 16; ++k) { S1 += rs[k]; S2 += rq[k]; }
    double mu = S1 / (double)LNSZ;
    double var = S2 / (double)LNSZ - mu * mu;
    smu = (float)mu;
    srstd = (float)(1.0 / sqrt(var + 1e-5));
  }
  __syncthreads();
  const float mu = smu, rstd = srstd;
  for (int idx = t; idx < LNSZ; idx += 1024) {
    float val = v[base + idx];
    out[base + idx] = (val - mu) * rstd * g2[idx] + b2[idx];
  }
}

extern "C" void kernel_launch(void* const* d_in, const int* in_sizes, int n_in,
                              void* d_out, int out_size, void* d_ws, size_t ws_size,
                              hipStream_t stream) {
  const float* x   = (const float*)d_in[0];
  const float* tw  = (const float*)d_in[1];
  const float* tb  = (const float*)d_in[2];
  const float* pw  = (const float*)d_in[3];
  const float* pb  = (const float*)d_in[4];
  const float* c1w = (const float*)d_in[5];
  const float* c2w = (const float*)d_in[6];
  const float* g1  = (const float*)d_in[7];
  const float* b1  = (const float*)d_in[8];
  const float* g2  = (const float*)d_in[9];
  const float* b2  = (const float*)d_in[10];

  float* ws   = (float*)d_ws;
  float* part = ws + PART_OFF;
  float* Th   = ws + TH_OFF;
  float* Pp   = ws + PP_OFF;
  float* D    = ws + D_OFF;
  float* S    = ws + S_OFF;
  float* y    = ws + Y_OFF;
  float* u    = ws + U_OFF;
  float* v    = ws + V_OFF;
  float* out  = (float*)d_out;

  // theta (o<256) + phi (o>=256) projections
  gemm_partial<<<dim3(4, NN), 256, 0, stream>>>(x, tw, pw, part);
  reduce_theta<<<3072, 256, 0, stream>>>(part, tb, Th);
  reduce_pool_phi<<<768, 256, 0, stream>>>(part, pb, Pp);
  // scores + max over pool windows + sum over queries
  dgemm<<<dim3(12, 48), 256, 0, stream>>>(Th, Pp, D);
  reduce_D<<<768, 256, 0, stream>>>(D, S);
  // attention apply + residual + LN1
  attn_ln1<<<NN, 1024, 0, stream>>>(x, S, g1, b1, y);
  // conv1 + relu
  gemm_partial<<<dim3(4, NN), 256, 0, stream>>>(y, c1w, c1w + 256 * CC, part);
  reduce_relu<<<6144, 256, 0, stream>>>(part, u);
  // conv2 + residual + LN2
  gemm_partial<<<dim3(4, NN), 256, 0, stream>>>(u, c2w, c2w + 256 * CC, part);
  final_ln2<<<NN, 1024, 0, stream>>>(part, y, g2, b2, v, out);
}

// Round 2
// 324.461 us; speedup vs baseline: 1.1335x; 1.1335x over previous
//
#include <hip/hip_runtime.h>

#define NN 64
#define CC 512
#define CIn 256
#define HW 48
#define LNSZ (CC * HW)   // 24576 elements per sample

// ---- workspace layout (float offsets) ----
static const size_t PART_OFF = 0;          // 4*64*48*512 = 6291456
static const size_t TH_OFF   = 6291456;    // 64*48*256
static const size_t PP_OFF   = 7077888;    // 64*12*256
static const size_t D_OFF    = 7274496;    // 3072*768 (free after reduce_D;
                                           // stats1/stats2 parked here later)
static const size_t S_OFF    = 9633792;    // 3072
static const size_t Y_OFF    = 9636864;    // 1572864
static const size_t U_OFF    = 11209728;   // 1572864
static const size_t V_OFF    = 12782592;   // 1572864
// total 14355456 floats = 57.4 MB (unchanged from round 1)

__device__ __forceinline__ float comp4(const float4& v, int d) {
  switch (d) {
    case 0: return v.x;
    case 1: return v.y;
    case 2: return v.z;
    default: return v.w;
  }
}

__device__ __forceinline__ void fma4(float4& a, float w, const float4& x) {
  a.x = fmaf(w, x.x, a.x);
  a.y = fmaf(w, x.y, a.y);
  a.z = fmaf(w, x.z, a.z);
  a.w = fmaf(w, x.w, a.w);
}

// block-level {sum, sumsq} reduction; valid result in thread 0
__device__ __forceinline__ void block_reduce2(float& sum, float& sq) {
  const int lane = threadIdx.x & 63, w = threadIdx.x >> 6;
#pragma unroll
  for (int off = 32; off > 0; off >>= 1) {
    sum += __shfl_down(sum, off, 64);
    sq  += __shfl_down(sq, off, 64);
  }
  __shared__ float rs[4], rq[4];
  if (lane == 0) { rs[w] = sum; rq[w] = sq; }
  __syncthreads();
  if (threadIdx.x == 0) {
    sum = rs[0] + rs[1] + rs[2] + rs[3];
    sq  = rq[0] + rq[1] + rq[2] + rq[3];
  }
}

// Generic per-sample GEMM with split-K partials (unchanged from round 1).
__global__ __launch_bounds__(256) void gemm_partial(
    const float* __restrict__ In, const float* __restrict__ W0,
    const float* __restrict__ W1, float* __restrict__ part) {
  const int ch = blockIdx.x;   // 0..3, c chunk of 128
  const int n  = blockIdx.y;   // 0..63
  const int t  = threadIdx.x;
  const int og = t & 127;
  const int sh = t >> 7;
  const int s0 = sh * 24;

  __shared__ __align__(16) float xs[128 * HW];  // 24 KB, [c_local][s]
  {
    const float4* src4 =
        (const float4*)(In + (size_t)n * LNSZ + (size_t)ch * 128 * HW);
    float4* xs4 = (float4*)xs;
#pragma unroll
    for (int k = 0; k < 6; ++k) xs4[t + k * 256] = src4[t + k * 256];
  }
  __syncthreads();

  const float* wrow[4];
#pragma unroll
  for (int k = 0; k < 4; ++k) {
    int o = og + 128 * k;
    wrow[k] = (o < 256 ? (W0 + (size_t)o * CC) : (W1 + (size_t)(o - 256) * CC))
              + ch * 128;
  }

  float4 acc[4][6];
#pragma unroll
  for (int k = 0; k < 4; ++k)
#pragma unroll
    for (int q = 0; q < 6; ++q) acc[k][q] = make_float4(0.f, 0.f, 0.f, 0.f);

  for (int cq = 0; cq < 32; ++cq) {
    float4 w4[4];
#pragma unroll
    for (int k = 0; k < 4; ++k) w4[k] = ((const float4*)wrow[k])[cq];
#pragma unroll
    for (int d = 0; d < 4; ++d) {
      const int c = cq * 4 + d;
      const float4* xrow = (const float4*)(xs + c * HW + s0);
      float4 xv[6];
#pragma unroll
      for (int q = 0; q < 6; ++q) xv[q] = xrow[q];
#pragma unroll
      for (int k = 0; k < 4; ++k) {
        const float w = comp4(w4[k], d);
#pragma unroll
        for (int q = 0; q < 6; ++q) fma4(acc[k][q], w, xv[q]);
      }
    }
  }

  float* pb = part + (size_t)(ch * NN + n) * (HW * CC);
#pragma unroll
  for (int k = 0; k < 4; ++k) {
    const int o = og + 128 * k;
#pragma unroll
    for (int q = 0; q < 6; ++q)
#pragma unroll
      for (int d = 0; d < 4; ++d) {
        const int s = s0 + q * 4 + d;
        pb[(size_t)s * CC + o] = comp4(acc[k][q], d);
      }
  }
}

// Th[(n*48+s)*256 + ci] = sum_ch part[ch][n][s][ci] + theta_b[ci]
__global__ __launch_bounds__(256) void reduce_theta(
    const float* __restrict__ part, const float* __restrict__ tb,
    float* __restrict__ Th) {
  int g = blockIdx.x * 256 + threadIdx.x;  // < 786432
  int ci = g & 255;
  int rest = g >> 8;        // n*48 + s
  int s = rest % HW;
  int n = rest / HW;
  float v = tb[ci];
#pragma unroll
  for (int ch = 0; ch < 4; ++ch)
    v += part[((size_t)(ch * NN + n) * HW + s) * CC + ci];
  Th[g] = v;
}

// Pp[(i*12+m)*256 + ci] = max over pooling window of (phi + phi_b)
__global__ __launch_bounds__(256) void reduce_pool_phi(
    const float* __restrict__ part, const float* __restrict__ pbias,
    float* __restrict__ Pp) {
  int g = blockIdx.x * 256 + threadIdx.x;  // < 196608
  int ci = g & 255;
  int rest = g >> 8;        // i*12 + m
  int m = rest % 12;
  int i = rest / 12;
  int sb = (m >> 1) * 8 + (m & 1) * 2;
  float bias = pbias[ci];
  float best = -3.4e38f;
  const int del[4] = {0, 1, 4, 5};
#pragma unroll
  for (int d = 0; d < 4; ++d) {
    int s = sb + del[d];
    float v = bias;
#pragma unroll
    for (int ch = 0; ch < 4; ++ch)
      v += part[((size_t)(ch * NN + i) * HW + s) * CC + 256 + ci];
    best = fmaxf(best, v);
  }
  Pp[g] = best;
}

// D[3072][768] = Th[3072][256] @ Pp[768][256]^T
__global__ __launch_bounds__(256) void dgemm(const float* __restrict__ A,
                                             const float* __restrict__ B,
                                             float* __restrict__ D) {
  __shared__ float As[64][33];
  __shared__ float Bs[64][33];
  const int t = threadIdx.x;
  const int r0 = blockIdx.y * 64;
  const int c0 = blockIdx.x * 64;
  const int tx = t & 15, ty = t >> 4;
  float acc[4][4] = {};
  for (int k0 = 0; k0 < 256; k0 += 32) {
    __syncthreads();
#pragma unroll
    for (int l = 0; l < 2; ++l) {
      int idx = t + l * 256;          // 0..511
      int r = idx >> 3;
      int kq = (idx & 7) * 4;
      float4 av = *(const float4*)(A + (size_t)(r0 + r) * 256 + k0 + kq);
      As[r][kq] = av.x; As[r][kq + 1] = av.y;
      As[r][kq + 2] = av.z; As[r][kq + 3] = av.w;
      float4 bv = *(const float4*)(B + (size_t)(c0 + r) * 256 + k0 + kq);
      Bs[r][kq] = bv.x; Bs[r][kq + 1] = bv.y;
      Bs[r][kq + 2] = bv.z; Bs[r][kq + 3] = bv.w;
    }
    __syncthreads();
#pragma unroll
    for (int k = 0; k < 32; ++k) {
      float a[4], b[4];
#pragma unroll
      for (int d = 0; d < 4; ++d) {
        a[d] = As[ty * 4 + d][k];
        b[d] = Bs[tx * 4 + d][k];
      }
#pragma unroll
      for (int i = 0; i < 4; ++i)
#pragma unroll
        for (int j = 0; j < 4; ++j) acc[i][j] = fmaf(a[i], b[j], acc[i][j]);
    }
  }
#pragma unroll
  for (int i = 0; i < 4; ++i) {
    float4 o = make_float4(acc[i][0], acc[i][1], acc[i][2], acc[i][3]);
    *(float4*)(D + (size_t)(r0 + ty * 4 + i) * 768 + c0 + tx * 4) = o;
  }
}

// S[row] = (1/12) * sum_i max_{m<12} D[row][i*12+m]
__global__ __launch_bounds__(256) void reduce_D(const float* __restrict__ D,
                                                float* __restrict__ S) {
  int w = threadIdx.x >> 6;
  int lane = threadIdx.x & 63;
  int row = blockIdx.x * 4 + w;   // < 3072
  const float* dr = D + (size_t)row * 768 + lane * 12;
  float4 a = *(const float4*)dr;
  float4 b = *(const float4*)(dr + 4);
  float4 c = *(const float4*)(dr + 8);
  float mx = a.x;
  mx = fmaxf(mx, a.y); mx = fmaxf(mx, a.z); mx = fmaxf(mx, a.w);
  mx = fmaxf(mx, b.x); mx = fmaxf(mx, b.y); mx = fmaxf(mx, b.z); mx = fmaxf(mx, b.w);
  mx = fmaxf(mx, c.x); mx = fmaxf(mx, c.y); mx = fmaxf(mx, c.z); mx = fmaxf(mx, c.w);
#pragma unroll
  for (int off = 32; off > 0; off >>= 1) mx += __shfl_down(mx, off, 64);
  if (lane == 0) S[row] = mx * (1.0f / 12.0f);
}

// ---- LN1 split into full-device stats + normalize passes ----
// e = x * (1 + S[s]) over [c][s] layout; per-(n, chunk of 3072) partials.
__global__ __launch_bounds__(256) void ln1_stats(
    const float* __restrict__ x, const float* __restrict__ S,
    float2* __restrict__ stats) {
  const int ch = blockIdx.x;  // 0..7
  const int n  = blockIdx.y;  // 0..63
  const int t  = threadIdx.x;
  __shared__ float sS[HW];
  if (t < HW) sS[t] = 1.0f + S[n * HW + t];
  __syncthreads();
  const float* xn = x + (size_t)n * LNSZ;
  float sum = 0.f, sq = 0.f;
#pragma unroll
  for (int k = 0; k < 3; ++k) {
    const int off = ch * 3072 + t * 4 + k * 1024;
    const int s0 = off % HW;
    float4 xv = *(const float4*)(xn + off);
    float e0 = xv.x * sS[s0];
    float e1 = xv.y * sS[s0 + 1];
    float e2 = xv.z * sS[s0 + 2];
    float e3 = xv.w * sS[s0 + 3];
    sum += (e0 + e1) + (e2 + e3);
    sq  += (e0 * e0 + e1 * e1) + (e2 * e2 + e3 * e3);
  }
  block_reduce2(sum, sq);
  if (t == 0) stats[n * 8 + ch] = make_float2(sum, sq);
}

__global__ __launch_bounds__(256) void ln1_norm(
    const float* __restrict__ x, const float* __restrict__ S,
    const float2* __restrict__ stats, const float* __restrict__ g,
    const float* __restrict__ b, float* __restrict__ y) {
  const int ch = blockIdx.x;
  const int n  = blockIdx.y;
  const int t  = threadIdx.x;
  __shared__ float sS[HW];
  __shared__ float smu, srstd;
  if (t < HW) sS[t] = 1.0f + S[n * HW + t];
  if (t == 0) {
    float s1 = 0.f, s2 = 0.f;
#pragma unroll
    for (int k = 0; k < 8; ++k) {
      float2 p = stats[n * 8 + k];
      s1 += p.x; s2 += p.y;
    }
    float mu = s1 * (1.0f / LNSZ);
    float var = s2 * (1.0f / LNSZ) - mu * mu;
    smu = mu;
    srstd = 1.0f / sqrtf(var + 1e-5f);
  }
  __syncthreads();
  const float mu = smu, rstd = srstd;
  const float* xn = x + (size_t)n * LNSZ;
  float* yn = y + (size_t)n * LNSZ;
#pragma unroll
  for (int k = 0; k < 3; ++k) {
    const int off = ch * 3072 + t * 4 + k * 1024;
    const int s0 = off % HW;
    float4 xv = *(const float4*)(xn + off);
    float4 gv = *(const float4*)(g + off);
    float4 bv = *(const float4*)(b + off);
    float4 o;
    o.x = (xv.x * sS[s0]     - mu) * rstd * gv.x + bv.x;
    o.y = (xv.y * sS[s0 + 1] - mu) * rstd * gv.y + bv.y;
    o.z = (xv.z * sS[s0 + 2] - mu) * rstd * gv.z + bv.z;
    o.w = (xv.w * sS[s0 + 3] - mu) * rstd * gv.w + bv.w;
    *(float4*)(yn + off) = o;
  }
}

// u[n][c][s] = relu(sum_ch part[ch][n][s][c])
__global__ __launch_bounds__(256) void reduce_relu(
    const float* __restrict__ part, float* __restrict__ u) {
  int g = blockIdx.x * 256 + threadIdx.x;  // < 1572864, order (n, s, c)
  int c = g & 511;
  int rest = g >> 9;        // n*48 + s
  int s = rest % HW;
  int n = rest / HW;
  float v = 0.f;
#pragma unroll
  for (int ch = 0; ch < 4; ++ch)
    v += part[((size_t)(ch * NN + n) * HW + s) * CC + c];
  u[((size_t)n * CC + c) * HW + s] = fmaxf(v, 0.f);
}

// ---- LN2: fused part-reduce + residual + stats, then normalize ----
// Iterates the per-sample [s][c] plane (part-coalesced); writes v in [c][s].
__global__ __launch_bounds__(256) void ln2_stats(
    const float* __restrict__ part, const float* __restrict__ y,
    float2* __restrict__ stats, float* __restrict__ v) {
  const int chb = blockIdx.x;  // 0..7 chunk of 3072 within the [s][c] plane
  const int n   = blockIdx.y;
  const int t   = threadIdx.x;
  const float* yn = y + (size_t)n * LNSZ;
  float* vn = v + (size_t)n * LNSZ;
  float sum = 0.f, sq = 0.f;
#pragma unroll
  for (int k = 0; k < 3; ++k) {
    const int off = chb * 3072 + t * 4 + k * 1024;
    const int s = off >> 9;
    const int c = off & 511;
    float4 p = make_float4(0.f, 0.f, 0.f, 0.f);
#pragma unroll
    for (int cc = 0; cc < 4; ++cc) {
      float4 pv = *(const float4*)(part +
          ((size_t)(cc * NN + n) * HW + s) * CC + c);
      p.x += pv.x; p.y += pv.y; p.z += pv.z; p.w += pv.w;
    }
    float v0 = p.x + yn[(c + 0) * HW + s];
    float v1 = p.y + yn[(c + 1) * HW + s];
    float v2 = p.z + yn[(c + 2) * HW + s];
    float v3 = p.w + yn[(c + 3) * HW + s];
    vn[(c + 0) * HW + s] = v0;
    vn[(c + 1) * HW + s] = v1;
    vn[(c + 2) * HW + s] = v2;
    vn[(c + 3) * HW + s] = v3;
    sum += (v0 + v1) + (v2 + v3);
    sq  += (v0 * v0 + v1 * v1) + (v2 * v2 + v3 * v3);
  }
  block_reduce2(sum, sq);
  if (t == 0) stats[n * 8 + chb] = make_float2(sum, sq);
}

__global__ __launch_bounds__(256) void ln2_norm(
    const float* __restrict__ v, const float2* __restrict__ stats,
    const float* __restrict__ g2, const float* __restrict__ b2,
    float* __restrict__ out) {
  const int ch = blockIdx.x;
  const int n  = blockIdx.y;
  const int t  = threadIdx.x;
  __shared__ float smu, srstd;
  if (t == 0) {
    float s1 = 0.f, s2 = 0.f;
#pragma unroll
    for (int k = 0; k < 8; ++k) {
      float2 p = stats[n * 8 + k];
      s1 += p.x; s2 += p.y;
    }
    float mu = s1 * (1.0f / LNSZ);
    float var = s2 * (1.0f / LNSZ) - mu * mu;
    smu = mu;
    srstd = 1.0f / sqrtf(var + 1e-5f);
  }
  __syncthreads();
  const float mu = smu, rstd = srstd;
  const float* vn = v + (size_t)n * LNSZ;
  float* on = out + (size_t)n * LNSZ;
#pragma unroll
  for (int k = 0; k < 3; ++k) {
    const int off = ch * 3072 + t * 4 + k * 1024;
    float4 vv = *(const float4*)(vn + off);
    float4 gv = *(const float4*)(g2 + off);
    float4 bv = *(const float4*)(b2 + off);
    float4 o;
    o.x = (vv.x - mu) * rstd * gv.x + bv.x;
    o.y = (vv.y - mu) * rstd * gv.y + bv.y;
    o.z = (vv.z - mu) * rstd * gv.z + bv.z;
    o.w = (vv.w - mu) * rstd * gv.w + bv.w;
    *(float4*)(on + off) = o;
  }
}

extern "C" void kernel_launch(void* const* d_in, const int* in_sizes, int n_in,
                              void* d_out, int out_size, void* d_ws, size_t ws_size,
                              hipStream_t stream) {
  const float* x   = (const float*)d_in[0];
  const float* tw  = (const float*)d_in[1];
  const float* tb  = (const float*)d_in[2];
  const float* pw  = (const float*)d_in[3];
  const float* pb  = (const float*)d_in[4];
  const float* c1w = (const float*)d_in[5];
  const float* c2w = (const float*)d_in[6];
  const float* g1  = (const float*)d_in[7];
  const float* b1  = (const float*)d_in[8];
  const float* g2  = (const float*)d_in[9];
  const float* b2  = (const float*)d_in[10];

  float* ws   = (float*)d_ws;
  float* part = ws + PART_OFF;
  float* Th   = ws + TH_OFF;
  float* Pp   = ws + PP_OFF;
  float* D    = ws + D_OFF;
  float* S    = ws + S_OFF;
  float* y    = ws + Y_OFF;
  float* u    = ws + U_OFF;
  float* v    = ws + V_OFF;
  // stats parked in the D region (D is dead after reduce_D)
  float2* stats1 = (float2*)(ws + D_OFF);
  float2* stats2 = (float2*)(ws + D_OFF + 2048);
  float* out  = (float*)d_out;

  // theta (o<256) + phi (o>=256) projections
  gemm_partial<<<dim3(4, NN), 256, 0, stream>>>(x, tw, pw, part);
  reduce_theta<<<3072, 256, 0, stream>>>(part, tb, Th);
  reduce_pool_phi<<<768, 256, 0, stream>>>(part, pb, Pp);
  // scores + max over pool windows + sum over queries
  dgemm<<<dim3(12, 48), 256, 0, stream>>>(Th, Pp, D);
  reduce_D<<<768, 256, 0, stream>>>(D, S);
  // attention apply + residual + LN1 (two full-device passes)
  ln1_stats<<<dim3(8, NN), 256, 0, stream>>>(x, S, stats1);
  ln1_norm<<<dim3(8, NN), 256, 0, stream>>>(x, S, stats1, g1, b1, y);
  // conv1 + relu
  gemm_partial<<<dim3(4, NN), 256, 0, stream>>>(y, c1w, c1w + 256 * CC, part);
  reduce_relu<<<6144, 256, 0, stream>>>(part, u);
  // conv2 + residual + LN2 (two full-device passes)
  gemm_partial<<<dim3(4, NN), 256, 0, stream>>>(u, c2w, c2w + 256 * CC, part);
  ln2_stats<<<dim3(8, NN), 256, 0, stream>>>(part, y, stats2, v);
  ln2_norm<<<dim3(8, NN), 256, 0, stream>>>(v, stats2, g2, b2, out);
}

// Round 4
// 161.309 us; speedup vs baseline: 2.2799x; 2.0114x over previous
//
#include <hip/hip_runtime.h>
#include <hip/hip_bf16.h>

#define NN 64
#define CC 512
#define HW 48
#define LNSZ (CC * HW)   // 24576 per sample

typedef __attribute__((ext_vector_type(8))) short bf16x8;  // 8 bf16 (4 VGPRs)
typedef __attribute__((ext_vector_type(4))) float floatx4;

// ---- workspace layout (float offsets) ----
static const size_t WB_OFF  = 0;         // 1536x512 bf16 = 393216 float-slots
static const size_t BC_OFF  = 393216;    // 512 fp32 (theta_b ++ phi_b)
static const size_t XB_OFF  = 393728;    // [64][48][512] bf16 = 786432 slots
static const size_t YB_OFF  = 1180160;   // same
static const size_t UB_OFF  = 1966592;   // same
static const size_t TH_OFF  = 2753024;   // [3072][256] bf16 = 393216 slots
static const size_t PP_OFF  = 3146240;   // [768][256] bf16 = 98304 slots
static const size_t PROJ_OFF= 3244544;   // [64][512][48] fp32 = 1572864
static const size_t DD_OFF  = 4817408;   // [3072][768] fp32 = 2359296
static const size_t SS_OFF  = 7176704;   // 3072
static const size_t YY_OFF  = 7179776;   // 1572864
static const size_t UU_OFF  = 8752640;   // 1572864
static const size_t HH_OFF  = 10325504;  // 1572864
static const size_t VV_OFF  = 11898368;  // 1572864
static const size_t ST1_OFF = 13471232;  // 1024
static const size_t ST2_OFF = 13472256;  // 1024
// total 13473280 floats = 53.9 MB

// block-level {sum, sumsq} reduction; valid result in thread 0
__device__ __forceinline__ void block_reduce2(float& sum, float& sq) {
  const int lane = threadIdx.x & 63, w = threadIdx.x >> 6;
#pragma unroll
  for (int off = 32; off > 0; off >>= 1) {
    sum += __shfl_down(sum, off, 64);
    sq  += __shfl_down(sq, off, 64);
  }
  __shared__ float rs[4], rq[4];
  if (lane == 0) { rs[w] = sum; rq[w] = sq; }
  __syncthreads();
  if (threadIdx.x == 0) {
    sum = rs[0] + rs[1] + rs[2] + rs[3];
    sq  = rq[0] + rq[1] + rq[2] + rq[3];
  }
}

// Pack weights into Wb bf16 [1536][512] (rows: tw 0-255, pw 256-511,
// c1 512-1023, c2 1024-1535) and theta/phi biases into bcat[512].
// NOTE: tw/pw are 256x512 (131072), c1/c2 are 512x512 (262144).
__global__ __launch_bounds__(256) void prep_w(
    const float* __restrict__ tw, const float* __restrict__ pw,
    const float* __restrict__ c1, const float* __restrict__ c2,
    const float* __restrict__ tb, const float* __restrict__ pb,
    __hip_bfloat16* __restrict__ Wb, float* __restrict__ bcat) {
  int g = blockIdx.x * 256 + threadIdx.x;  // < 786432
  float v;
  if (g < 131072)      v = tw[g];
  else if (g < 262144) v = pw[g - 131072];
  else if (g < 524288) v = c1[g - 262144];
  else                 v = c2[g - 524288];
  Wb[g] = __float2bfloat16(v);
  if (g < 512) bcat[g] = g < 256 ? tb[g] : pb[g - 256];
}

// Transpose+convert: in fp32 [n-plane][C][48] -> out bf16 [n-plane][48][rowstr]
// (block covers a 128-channel chunk; grid (chunks, n))
__global__ __launch_bounds__(256) void tr_bf16(
    const float* __restrict__ in, __hip_bfloat16* __restrict__ out,
    int in_nstride, int out_nstride, int rowstr) {
  const int c0 = blockIdx.x * 128;
  const int n  = blockIdx.y;
  const int t  = threadIdx.x;
  __shared__ float ts[128 * 49];
  const float* src = in + (size_t)n * in_nstride + (size_t)c0 * HW;
#pragma unroll
  for (int k = 0; k < 6; ++k) {
    int idx = t + k * 256;               // float4 index over 1536
    float4 v = ((const float4*)src)[idx];
    int c = idx / 12, sq = (idx % 12) * 4;
    float* d = ts + c * 49 + sq;
    d[0] = v.x; d[1] = v.y; d[2] = v.z; d[3] = v.w;
  }
  __syncthreads();
  __hip_bfloat16* dst = out + (size_t)n * out_nstride + c0;
#pragma unroll
  for (int k = 0; k < 12; ++k) {
    int idx = t + k * 256;               // ushort2 index over 3072
    int s = idx >> 6, cp = idx & 63;
    __hip_bfloat162 p;
    p.x = __float2bfloat16(ts[(cp * 2) * 49 + s]);
    p.y = __float2bfloat16(ts[(cp * 2 + 1) * 49 + s]);
    *(__hip_bfloat162*)(dst + (size_t)s * rowstr + cp * 2) = p;
  }
}

// MFMA conv GEMM (per-sample): out[n][o][s] = sum_c Wb[o][c] * inb[n][s][c]
// + optional bias[o], optional relu. M=512 o, N=48 s, K=512.
// Grid (4 o-chunks, 64 n), 256 thr = 4 waves; wave = 32 o x 48 s (2x3 tiles).
__global__ __launch_bounds__(256) void gemm_conv(
    const __hip_bfloat16* __restrict__ Wb, const __hip_bfloat16* __restrict__ inb,
    const float* __restrict__ bias, float* __restrict__ out, int relu) {
  const int oc = blockIdx.x, n = blockIdx.y;
  const int w = threadIdx.x >> 6, lane = threadIdx.x & 63;
  const int c16 = lane & 15, quad = lane >> 4;
  const int obase = oc * 128 + w * 32;

  const __hip_bfloat16* A0 = Wb + (size_t)(obase + c16) * 512 + quad * 8;
  const __hip_bfloat16* A1 = A0 + 16 * 512;
  const __hip_bfloat16* B0 = inb + (size_t)n * LNSZ + (size_t)c16 * 512 + quad * 8;

  floatx4 zero = {0.f, 0.f, 0.f, 0.f};
  floatx4 acc[2][3];
#pragma unroll
  for (int i = 0; i < 2; ++i)
#pragma unroll
    for (int j = 0; j < 3; ++j) acc[i][j] = zero;

  bf16x8 a[2], b[3];
  a[0] = *(const bf16x8*)(A0);
  a[1] = *(const bf16x8*)(A1);
  b[0] = *(const bf16x8*)(B0);
  b[1] = *(const bf16x8*)(B0 + 16 * 512);
  b[2] = *(const bf16x8*)(B0 + 32 * 512);

  for (int k = 0; k < 480; k += 32) {
    bf16x8 an[2], bn[3];
    const int k2 = k + 32;
    an[0] = *(const bf16x8*)(A0 + k2);
    an[1] = *(const bf16x8*)(A1 + k2);
    bn[0] = *(const bf16x8*)(B0 + k2);
    bn[1] = *(const bf16x8*)(B0 + 16 * 512 + k2);
    bn[2] = *(const bf16x8*)(B0 + 32 * 512 + k2);
#pragma unroll
    for (int i = 0; i < 2; ++i)
#pragma unroll
      for (int j = 0; j < 3; ++j)
        acc[i][j] = __builtin_amdgcn_mfma_f32_16x16x32_bf16(a[i], b[j],
                                                            acc[i][j], 0, 0, 0);
    a[0] = an[0]; a[1] = an[1];
    b[0] = bn[0]; b[1] = bn[1]; b[2] = bn[2];
  }
#pragma unroll
  for (int i = 0; i < 2; ++i)
#pragma unroll
    for (int j = 0; j < 3; ++j)
      acc[i][j] = __builtin_amdgcn_mfma_f32_16x16x32_bf16(a[i], b[j],
                                                          acc[i][j], 0, 0, 0);

  float* on = out + (size_t)n * LNSZ;
#pragma unroll
  for (int i = 0; i < 2; ++i) {
#pragma unroll
    for (int r = 0; r < 4; ++r) {
      const int o = obase + i * 16 + quad * 4 + r;
      const float bv = bias ? bias[o] : 0.f;
#pragma unroll
      for (int j = 0; j < 3; ++j) {
        float v = acc[i][j][r] + bv;
        if (relu) v = fmaxf(v, 0.f);
        on[(size_t)o * HW + j * 16 + c16] = v;
      }
    }
  }
}

// Pp[(i*12+m)][ci] = max over 2x2 window of proj[i][256+ci][s] (bias included)
__global__ __launch_bounds__(256) void make_pp(
    const float* __restrict__ proj, __hip_bfloat16* __restrict__ Pp) {
  int g = blockIdx.x * 256 + threadIdx.x;  // < 196608
  int ci = g & 255;
  int rest = g >> 8;
  int m = rest % 12, i = rest / 12;
  int sb = (m >> 1) * 8 + (m & 1) * 2;
  const float* row = proj + (size_t)i * LNSZ + (size_t)(256 + ci) * HW;
  float2 p0 = *(const float2*)(row + sb);
  float2 p1 = *(const float2*)(row + sb + 4);
  float mx = fmaxf(fmaxf(p0.x, p0.y), fmaxf(p1.x, p1.y));
  Pp[g] = __float2bfloat16(mx);
}

// D[3072][768] = Th[3072][256] @ Pp[768][256]^T (bf16 MFMA)
// Grid (16 n-chunks of 48, 24 m-chunks of 128); wave = 32 m x 48 n.
__global__ __launch_bounds__(256) void dgemm_mfma(
    const __hip_bfloat16* __restrict__ A, const __hip_bfloat16* __restrict__ B,
    float* __restrict__ D) {
  const int bn = blockIdx.x * 48;
  const int w = threadIdx.x >> 6, lane = threadIdx.x & 63;
  const int c16 = lane & 15, quad = lane >> 4;
  const int bm = blockIdx.y * 128 + w * 32;

  const __hip_bfloat16* A0 = A + (size_t)(bm + c16) * 256 + quad * 8;
  const __hip_bfloat16* A1 = A0 + 16 * 256;
  const __hip_bfloat16* Bp = B + (size_t)(bn + c16) * 256 + quad * 8;

  floatx4 zero = {0.f, 0.f, 0.f, 0.f};
  floatx4 acc[2][3];
#pragma unroll
  for (int i = 0; i < 2; ++i)
#pragma unroll
    for (int j = 0; j < 3; ++j) acc[i][j] = zero;

#pragma unroll 2
  for (int k = 0; k < 256; k += 32) {
    bf16x8 a0 = *(const bf16x8*)(A0 + k);
    bf16x8 a1 = *(const bf16x8*)(A1 + k);
    bf16x8 b0 = *(const bf16x8*)(Bp + k);
    bf16x8 b1 = *(const bf16x8*)(Bp + 16 * 256 + k);
    bf16x8 b2 = *(const bf16x8*)(Bp + 32 * 256 + k);
    acc[0][0] = __builtin_amdgcn_mfma_f32_16x16x32_bf16(a0, b0, acc[0][0], 0, 0, 0);
    acc[0][1] = __builtin_amdgcn_mfma_f32_16x16x32_bf16(a0, b1, acc[0][1], 0, 0, 0);
    acc[0][2] = __builtin_amdgcn_mfma_f32_16x16x32_bf16(a0, b2, acc[0][2], 0, 0, 0);
    acc[1][0] = __builtin_amdgcn_mfma_f32_16x16x32_bf16(a1, b0, acc[1][0], 0, 0, 0);
    acc[1][1] = __builtin_amdgcn_mfma_f32_16x16x32_bf16(a1, b1, acc[1][1], 0, 0, 0);
    acc[1][2] = __builtin_amdgcn_mfma_f32_16x16x32_bf16(a1, b2, acc[1][2], 0, 0, 0);
  }

#pragma unroll
  for (int i = 0; i < 2; ++i)
#pragma unroll
    for (int r = 0; r < 4; ++r) {
      const int row = bm + i * 16 + quad * 4 + r;
#pragma unroll
      for (int j = 0; j < 3; ++j)
        D[(size_t)row * 768 + bn + j * 16 + c16] = acc[i][j][r];
    }
}

// S[row] = (1/12) * sum_i max_{m<12} D[row][i*12+m]
__global__ __launch_bounds__(256) void reduce_D(const float* __restrict__ D,
                                                float* __restrict__ S) {
  int w = threadIdx.x >> 6;
  int lane = threadIdx.x & 63;
  int row = blockIdx.x * 4 + w;   // < 3072
  const float* dr = D + (size_t)row * 768 + lane * 12;
  float4 a = *(const float4*)dr;
  float4 b = *(const float4*)(dr + 4);
  float4 c = *(const float4*)(dr + 8);
  float mx = a.x;
  mx = fmaxf(mx, a.y); mx = fmaxf(mx, a.z); mx = fmaxf(mx, a.w);
  mx = fmaxf(mx, b.x); mx = fmaxf(mx, b.y); mx = fmaxf(mx, b.z); mx = fmaxf(mx, b.w);
  mx = fmaxf(mx, c.x); mx = fmaxf(mx, c.y); mx = fmaxf(mx, c.z); mx = fmaxf(mx, c.w);
#pragma unroll
  for (int off = 32; off > 0; off >>= 1) mx += __shfl_down(mx, off, 64);
  if (lane == 0) S[row] = mx * (1.0f / 12.0f);
}

// LN1 stats over e = x * (1 + S[s]) in [c][s] layout
__global__ __launch_bounds__(256) void ln1_stats(
    const float* __restrict__ x, const float* __restrict__ S,
    float2* __restrict__ stats) {
  const int ch = blockIdx.x, n = blockIdx.y, t = threadIdx.x;
  __shared__ float sS[HW];
  if (t < HW) sS[t] = 1.0f + S[n * HW + t];
  __syncthreads();
  const float* xn = x + (size_t)n * LNSZ;
  float sum = 0.f, sq = 0.f;
#pragma unroll
  for (int k = 0; k < 3; ++k) {
    const int off = ch * 3072 + t * 4 + k * 1024;
    const int s0 = off % HW;
    float4 xv = *(const float4*)(xn + off);
    float e0 = xv.x * sS[s0];
    float e1 = xv.y * sS[s0 + 1];
    float e2 = xv.z * sS[s0 + 2];
    float e3 = xv.w * sS[s0 + 3];
    sum += (e0 + e1) + (e2 + e3);
    sq  += (e0 * e0 + e1 * e1) + (e2 * e2 + e3 * e3);
  }
  block_reduce2(sum, sq);
  if (t == 0) stats[n * 8 + ch] = make_float2(sum, sq);
}

__global__ __launch_bounds__(256) void ln1_norm(
    const float* __restrict__ x, const float* __restrict__ S,
    const float2* __restrict__ stats, const float* __restrict__ g,
    const float* __restrict__ b, float* __restrict__ y) {
  const int ch = blockIdx.x, n = blockIdx.y, t = threadIdx.x;
  __shared__ float sS[HW];
  __shared__ float smu, srstd;
  if (t < HW) sS[t] = 1.0f + S[n * HW + t];
  if (t == 0) {
    float s1 = 0.f, s2 = 0.f;
#pragma unroll
    for (int k = 0; k < 8; ++k) {
      float2 p = stats[n * 8 + k];
      s1 += p.x; s2 += p.y;
    }
    float mu = s1 * (1.0f / LNSZ);
    float var = s2 * (1.0f / LNSZ) - mu * mu;
    smu = mu;
    srstd = 1.0f / sqrtf(var + 1e-5f);
  }
  __syncthreads();
  const float mu = smu, rstd = srstd;
  const float* xn = x + (size_t)n * LNSZ;
  float* yn = y + (size_t)n * LNSZ;
#pragma unroll
  for (int k = 0; k < 3; ++k) {
    const int off = ch * 3072 + t * 4 + k * 1024;
    const int s0 = off % HW;
    float4 xv = *(const float4*)(xn + off);
    float4 gv = *(const float4*)(g + off);
    float4 bv = *(const float4*)(b + off);
    float4 o;
    o.x = (xv.x * sS[s0]     - mu) * rstd * gv.x + bv.x;
    o.y = (xv.y * sS[s0 + 1] - mu) * rstd * gv.y + bv.y;
    o.z = (xv.z * sS[s0 + 2] - mu) * rstd * gv.z + bv.z;
    o.w = (xv.w * sS[s0 + 3] - mu) * rstd * gv.w + bv.w;
    *(float4*)(yn + off) = o;
  }
}

// LN2 stats over v = y + h (both [n][c][s] fp32); writes v
__global__ __launch_bounds__(256) void ln2_stats(
    const float* __restrict__ y, const float* __restrict__ h,
    float2* __restrict__ stats, float* __restrict__ v) {
  const int ch = blockIdx.x, n = blockIdx.y, t = threadIdx.x;
  const size_t base = (size_t)n * LNSZ;
  float sum = 0.f, sq = 0.f;
#pragma unroll
  for (int k = 0; k < 3; ++k) {
    const int off = ch * 3072 + t * 4 + k * 1024;
    float4 yv = *(const float4*)(y + base + off);
    float4 hv = *(const float4*)(h + base + off);
    float v0 = yv.x + hv.x, v1 = yv.y + hv.y;
    float v2 = yv.z + hv.z, v3 = yv.w + hv.w;
    float4 o = make_float4(v0, v1, v2, v3);
    *(float4*)(v + base + off) = o;
    sum += (v0 + v1) + (v2 + v3);
    sq  += (v0 * v0 + v1 * v1) + (v2 * v2 + v3 * v3);
  }
  block_reduce2(sum, sq);
  if (t == 0) stats[n * 8 + ch] = make_float2(sum, sq);
}

__global__ __launch_bounds__(256) void ln2_norm(
    const float* __restrict__ v, const float2* __restrict__ stats,
    const float* __restrict__ g2, const float* __restrict__ b2,
    float* __restrict__ out) {
  const int ch = blockIdx.x, n = blockIdx.y, t = threadIdx.x;
  __shared__ float smu, srstd;
  if (t == 0) {
    float s1 = 0.f, s2 = 0.f;
#pragma unroll
    for (int k = 0; k < 8; ++k) {
      float2 p = stats[n * 8 + k];
      s1 += p.x; s2 += p.y;
    }
    float mu = s1 * (1.0f / LNSZ);
    float var = s2 * (1.0f / LNSZ) - mu * mu;
    smu = mu;
    srstd = 1.0f / sqrtf(var + 1e-5f);
  }
  __syncthreads();
  const float mu = smu, rstd = srstd;
  const float* vn = v + (size_t)n * LNSZ;
  float* on = out + (size_t)n * LNSZ;
#pragma unroll
  for (int k = 0; k < 3; ++k) {
    const int off = ch * 3072 + t * 4 + k * 1024;
    float4 vv = *(const float4*)(vn + off);
    float4 gv = *(const float4*)(g2 + off);
    float4 bv = *(const float4*)(b2 + off);
    float4 o;
    o.x = (vv.x - mu) * rstd * gv.x + bv.x;
    o.y = (vv.y - mu) * rstd * gv.y + bv.y;
    o.z = (vv.z - mu) * rstd * gv.z + bv.z;
    o.w = (vv.w - mu) * rstd * gv.w + bv.w;
    *(float4*)(on + off) = o;
  }
}

extern "C" void kernel_launch(void* const* d_in, const int* in_sizes, int n_in,
                              void* d_out, int out_size, void* d_ws, size_t ws_size,
                              hipStream_t stream) {
  const float* x   = (const float*)d_in[0];
  const float* tw  = (const float*)d_in[1];
  const float* tb  = (const float*)d_in[2];
  const float* pw  = (const float*)d_in[3];
  const float* pb  = (const float*)d_in[4];
  const float* c1w = (const float*)d_in[5];
  const float* c2w = (const float*)d_in[6];
  const float* g1  = (const float*)d_in[7];
  const float* b1  = (const float*)d_in[8];
  const float* g2  = (const float*)d_in[9];
  const float* b2  = (const float*)d_in[10];

  float* ws = (float*)d_ws;
  __hip_bfloat16* Wb = (__hip_bfloat16*)(ws + WB_OFF);
  float* bcat        = ws + BC_OFF;
  __hip_bfloat16* xb = (__hip_bfloat16*)(ws + XB_OFF);
  __hip_bfloat16* yb = (__hip_bfloat16*)(ws + YB_OFF);
  __hip_bfloat16* ub = (__hip_bfloat16*)(ws + UB_OFF);
  __hip_bfloat16* Th = (__hip_bfloat16*)(ws + TH_OFF);
  __hip_bfloat16* Pp = (__hip_bfloat16*)(ws + PP_OFF);
  float* proj = ws + PROJ_OFF;
  float* D    = ws + DD_OFF;
  float* S    = ws + SS_OFF;
  float* y    = ws + YY_OFF;
  float* u    = ws + UU_OFF;
  float* h    = ws + HH_OFF;
  float* v    = ws + VV_OFF;
  float2* st1 = (float2*)(ws + ST1_OFF);
  float2* st2 = (float2*)(ws + ST2_OFF);
  float* out  = (float*)d_out;

  // weight/bias packing + x transpose to bf16 [n][s][c]
  prep_w<<<3072, 256, 0, stream>>>(tw, pw, c1w, c2w, tb, pb, Wb, bcat);
  tr_bf16<<<dim3(4, NN), 256, 0, stream>>>(x, xb, LNSZ, LNSZ, 512);
  // theta+phi projection (rows 0..255 theta, 256..511 phi), bias fused
  gemm_conv<<<dim3(4, NN), 256, 0, stream>>>(Wb, xb, bcat, proj, 0);
  // Th = transpose of theta rows -> bf16 [(n,s)][ci]; Pp = pooled phi
  tr_bf16<<<dim3(2, NN), 256, 0, stream>>>(proj, Th, LNSZ, 48 * 256, 256);
  make_pp<<<768, 256, 0, stream>>>(proj, Pp);
  // scores + pool-max + query-sum
  dgemm_mfma<<<dim3(16, 24), 256, 0, stream>>>(Th, Pp, D);
  reduce_D<<<768, 256, 0, stream>>>(D, S);
  // attention apply + residual + LN1
  ln1_stats<<<dim3(8, NN), 256, 0, stream>>>(x, S, st1);
  ln1_norm<<<dim3(8, NN), 256, 0, stream>>>(x, S, st1, g1, b1, y);
  tr_bf16<<<dim3(4, NN), 256, 0, stream>>>(y, yb, LNSZ, LNSZ, 512);
  // conv1 + relu (fused epilogue)
  gemm_conv<<<dim3(4, NN), 256, 0, stream>>>(Wb + 512 * 512, yb, nullptr, u, 1);
  tr_bf16<<<dim3(4, NN), 256, 0, stream>>>(u, ub, LNSZ, LNSZ, 512);
  // conv2
  gemm_conv<<<dim3(4, NN), 256, 0, stream>>>(Wb + 1024 * 512, ub, nullptr, h, 0);
  // residual + LN2
  ln2_stats<<<dim3(8, NN), 256, 0, stream>>>(y, h, st2, v);
  ln2_norm<<<dim3(8, NN), 256, 0, stream>>>(v, st2, g2, b2, out);
}

// Round 5
// 140.601 us; speedup vs baseline: 2.6157x; 1.1473x over previous
//
#include <hip/hip_runtime.h>
#include <hip/hip_bf16.h>

#define NN 64
#define CC 512
#define HW 48
#define LNSZ (CC * HW)   // 24576 per sample

typedef __attribute__((ext_vector_type(8))) short bf16x8;  // 8 bf16 (4 VGPRs)
typedef __attribute__((ext_vector_type(4))) float floatx4;

// ---- workspace layout (float offsets) ----
static const size_t WB_OFF   = 0;        // 1536x512 bf16 = 393216 float-slots
static const size_t BC_OFF   = 393216;   // 512 fp32 biases (theta ++ phi)
static const size_t S_OFF    = 393728;   // 3072 fp32 (attention scale, atomic)
static const size_t SMU_OFF  = 396800;   // 64
static const size_t SRS_OFF  = 396864;   // 64
static const size_t CXP_OFF  = 396928;   // [64][4][48] colsum partials
static const size_t CX2_OFF  = 409216;   // [64][4][48] colsumsq partials
static const size_t ST2_OFF  = 421504;   // [64][4] float2 ln2 stats
static const size_t XB_OFF   = 422016;   // [64][48][512] bf16 = 786432 slots
static const size_t TP_OFF   = 1208448;  // ThPhi bf16 [64][48][512]
static const size_t YB_OFF   = 1994880;  // yb bf16 [64][48][512]
static const size_t UB_OFF   = 2781312;  // ub bf16 [64][48][512]
static const size_t PP_OFF   = 3567744;  // Pp bf16 [768][256] = 98304 slots
static const size_t YY_OFF   = 3666048;  // y fp32 [64][512][48]
static const size_t VV_OFF   = 5238912;  // v fp32 [64][512][48]
// total 6811776 floats = 27.2 MB

// block-level {sum, sumsq} reduction; valid result in thread 0
__device__ __forceinline__ void block_reduce2(float& sum, float& sq) {
  const int lane = threadIdx.x & 63, w = threadIdx.x >> 6;
#pragma unroll
  for (int off = 32; off > 0; off >>= 1) {
    sum += __shfl_down(sum, off, 64);
    sq  += __shfl_down(sq, off, 64);
  }
  __shared__ float rs[4], rq[4];
  if (lane == 0) { rs[w] = sum; rq[w] = sq; }
  __syncthreads();
  if (threadIdx.x == 0) {
    sum = rs[0] + rs[1] + rs[2] + rs[3];
    sq  = rq[0] + rq[1] + rq[2] + rq[3];
  }
}

// Pack weights into Wb bf16 [1536][512] (tw 0-255, pw 256-511, c1 512-1023,
// c2 1024-1535), biases into bcat[512], and zero the S accumulator.
__global__ __launch_bounds__(256) void prep_w(
    const float* __restrict__ tw, const float* __restrict__ pw,
    const float* __restrict__ c1, const float* __restrict__ c2,
    const float* __restrict__ tb, const float* __restrict__ pb,
    __hip_bfloat16* __restrict__ Wb, float* __restrict__ bcat,
    float* __restrict__ S) {
  int g = blockIdx.x * 256 + threadIdx.x;  // < 786432
  float v;
  if (g < 131072)      v = tw[g];
  else if (g < 262144) v = pw[g - 131072];
  else if (g < 524288) v = c1[g - 262144];
  else                 v = c2[g - 524288];
  Wb[g] = __float2bfloat16(v);
  if (g < 512) bcat[g] = g < 256 ? tb[g] : pb[g - 256];
  if (g < 3072) S[g] = 0.f;
}

// x fp32 [n][C][48] -> xb bf16 [n][48][512], plus per-(n,chunk,s) column
// sums/sumsq of x (for LN1 stats-for-free).
__global__ __launch_bounds__(256) void trx_stats(
    const float* __restrict__ x, __hip_bfloat16* __restrict__ xb,
    float* __restrict__ cxp, float* __restrict__ cx2p) {
  const int bx = blockIdx.x;   // c-chunk of 128
  const int n  = blockIdx.y;
  const int t  = threadIdx.x;
  __shared__ float ts[128 * 49];
  __shared__ float ps[192], pq[192];
  const float* src = x + (size_t)n * LNSZ + (size_t)bx * 128 * HW;
#pragma unroll
  for (int k = 0; k < 6; ++k) {
    int idx = t + k * 256;               // float4 index over 1536
    float4 v = ((const float4*)src)[idx];
    int c = idx / 12, sq = (idx % 12) * 4;
    float* d = ts + c * 49 + sq;
    d[0] = v.x; d[1] = v.y; d[2] = v.z; d[3] = v.w;
  }
  __syncthreads();
  // column-sum partials: 192 threads, each sums 32 c's for one s
  if (t < 192) {
    int s = t % 48, q = t / 48;
    float sum = 0.f, sq2 = 0.f;
#pragma unroll
    for (int c = q * 32; c < q * 32 + 32; ++c) {
      float v = ts[c * 49 + s];
      sum += v; sq2 += v * v;
    }
    ps[t] = sum; pq[t] = sq2;
  }
  // transposed bf16 writes
  __hip_bfloat16* dst = xb + (size_t)n * LNSZ + bx * 128;
#pragma unroll
  for (int k = 0; k < 12; ++k) {
    int idx = t + k * 256;
    int s = idx >> 6, cp = idx & 63;
    __hip_bfloat162 p;
    p.x = __float2bfloat16(ts[(cp * 2) * 49 + s]);
    p.y = __float2bfloat16(ts[(cp * 2 + 1) * 49 + s]);
    *(__hip_bfloat162*)(dst + (size_t)s * 512 + cp * 2) = p;
  }
  __syncthreads();
  if (t < 48) {
    cxp[((size_t)n * 4 + bx) * 48 + t] = ps[t] + ps[48 + t] + ps[96 + t] + ps[144 + t];
    cx2p[((size_t)n * 4 + bx) * 48 + t] = pq[t] + pq[48 + t] + pq[96 + t] + pq[144 + t];
  }
}

// MFMA GEMM (per-sample), transposed bf16 output:
// outb[n][s][o] = bf16( sum_c Wb[o][c] * inb[n][s][c] + bias[o] ), opt relu.
// Grid (4 o-chunks, 64 n), 256 thr; wave = 32 o x 48 s.
__global__ __launch_bounds__(256) void gemm_bf16out(
    const __hip_bfloat16* __restrict__ Wb, const __hip_bfloat16* __restrict__ inb,
    const float* __restrict__ bias, __hip_bfloat16* __restrict__ outb, int relu) {
  const int oc = blockIdx.x, n = blockIdx.y;
  const int w = threadIdx.x >> 6, lane = threadIdx.x & 63;
  const int c16 = lane & 15, quad = lane >> 4;
  const int obase = oc * 128 + w * 32;

  const __hip_bfloat16* A0 = Wb + (size_t)(obase + c16) * 512 + quad * 8;
  const __hip_bfloat16* A1 = A0 + 16 * 512;
  const __hip_bfloat16* B0 = inb + (size_t)n * LNSZ + (size_t)c16 * 512 + quad * 8;

  floatx4 zero = {0.f, 0.f, 0.f, 0.f};
  floatx4 acc[2][3];
#pragma unroll
  for (int i = 0; i < 2; ++i)
#pragma unroll
    for (int j = 0; j < 3; ++j) acc[i][j] = zero;

  bf16x8 a[2], b[3];
  a[0] = *(const bf16x8*)(A0);
  a[1] = *(const bf16x8*)(A1);
  b[0] = *(const bf16x8*)(B0);
  b[1] = *(const bf16x8*)(B0 + 16 * 512);
  b[2] = *(const bf16x8*)(B0 + 32 * 512);

  for (int k = 0; k < 480; k += 32) {
    bf16x8 an[2], bn[3];
    const int k2 = k + 32;
    an[0] = *(const bf16x8*)(A0 + k2);
    an[1] = *(const bf16x8*)(A1 + k2);
    bn[0] = *(const bf16x8*)(B0 + k2);
    bn[1] = *(const bf16x8*)(B0 + 16 * 512 + k2);
    bn[2] = *(const bf16x8*)(B0 + 32 * 512 + k2);
#pragma unroll
    for (int i = 0; i < 2; ++i)
#pragma unroll
      for (int j = 0; j < 3; ++j)
        acc[i][j] = __builtin_amdgcn_mfma_f32_16x16x32_bf16(a[i], b[j],
                                                            acc[i][j], 0, 0, 0);
    a[0] = an[0]; a[1] = an[1];
    b[0] = bn[0]; b[1] = bn[1]; b[2] = bn[2];
  }
#pragma unroll
  for (int i = 0; i < 2; ++i)
#pragma unroll
    for (int j = 0; j < 3; ++j)
      acc[i][j] = __builtin_amdgcn_mfma_f32_16x16x32_bf16(a[i], b[j],
                                                          acc[i][j], 0, 0, 0);

  __hip_bfloat16* on = outb + (size_t)n * LNSZ;
#pragma unroll
  for (int i = 0; i < 2; ++i) {
    const int o0 = obase + i * 16 + quad * 4;
    float bv[4];
#pragma unroll
    for (int r = 0; r < 4; ++r) bv[r] = bias ? bias[o0 + r] : 0.f;
#pragma unroll
    for (int j = 0; j < 3; ++j) {
      const int s = j * 16 + c16;
      union { short4 s4; __hip_bfloat16 h[4]; } u;
#pragma unroll
      for (int r = 0; r < 4; ++r) {
        float v = acc[i][j][r] + bv[r];
        if (relu) v = fmaxf(v, 0.f);
        u.h[r] = __float2bfloat16(v);
      }
      *(short4*)(on + (size_t)s * 512 + o0) = u.s4;
    }
  }
}

// Pp[(i*12+m)][ci] = max over 2x2 window of ThPhi[i][s][256+ci]
__global__ __launch_bounds__(256) void make_pp(
    const __hip_bfloat16* __restrict__ ThPhi, __hip_bfloat16* __restrict__ Pp) {
  int g = blockIdx.x * 256 + threadIdx.x;  // < 196608
  int ci = g & 255;
  int rest = g >> 8;
  int m = rest % 12, i = rest / 12;
  int sb = (m >> 1) * 8 + (m & 1) * 2;
  const __hip_bfloat16* base = ThPhi + (size_t)i * LNSZ + 256 + ci;
  float mx = __bfloat162float(base[(size_t)(sb + 0) * 512]);
  mx = fmaxf(mx, __bfloat162float(base[(size_t)(sb + 1) * 512]));
  mx = fmaxf(mx, __bfloat162float(base[(size_t)(sb + 4) * 512]));
  mx = fmaxf(mx, __bfloat162float(base[(size_t)(sb + 5) * 512]));
  Pp[g] = __float2bfloat16(mx);
}

// Score GEMM with fused pool-max + query-sum:
// S[row] += (1/12) * sum_{i in block} max_{m<12} (Th[row] . Pp[i*12+m])
// A = ThPhi rows (n,s), stride 512, first 256 cols; B = Pp [768][256].
// Grid (16 col-blocks of 48, 24 row-blocks of 128); wave = 32 rows x 48 cols.
__global__ __launch_bounds__(256) void dgemm_fused(
    const __hip_bfloat16* __restrict__ A, const __hip_bfloat16* __restrict__ B,
    float* __restrict__ S) {
  const int bn = blockIdx.x * 48;
  const int w = threadIdx.x >> 6, lane = threadIdx.x & 63;
  const int c16 = lane & 15, quad = lane >> 4;
  const int bm = blockIdx.y * 128 + w * 32;

  const __hip_bfloat16* A0 = A + (size_t)(bm + c16) * 512 + quad * 8;
  const __hip_bfloat16* A1 = A0 + 16 * 512;
  const __hip_bfloat16* Bp = B + (size_t)(bn + c16) * 256 + quad * 8;

  floatx4 zero = {0.f, 0.f, 0.f, 0.f};
  floatx4 acc[2][3];
#pragma unroll
  for (int i = 0; i < 2; ++i)
#pragma unroll
    for (int j = 0; j < 3; ++j) acc[i][j] = zero;

#pragma unroll 2
  for (int k = 0; k < 256; k += 32) {
    bf16x8 a0 = *(const bf16x8*)(A0 + k);
    bf16x8 a1 = *(const bf16x8*)(A1 + k);
    bf16x8 b0 = *(const bf16x8*)(Bp + k);
    bf16x8 b1 = *(const bf16x8*)(Bp + 16 * 256 + k);
    bf16x8 b2 = *(const bf16x8*)(Bp + 32 * 256 + k);
    acc[0][0] = __builtin_amdgcn_mfma_f32_16x16x32_bf16(a0, b0, acc[0][0], 0, 0, 0);
    acc[0][1] = __builtin_amdgcn_mfma_f32_16x16x32_bf16(a0, b1, acc[0][1], 0, 0, 0);
    acc[0][2] = __builtin_amdgcn_mfma_f32_16x16x32_bf16(a0, b2, acc[0][2], 0, 0, 0);
    acc[1][0] = __builtin_amdgcn_mfma_f32_16x16x32_bf16(a1, b0, acc[1][0], 0, 0, 0);
    acc[1][1] = __builtin_amdgcn_mfma_f32_16x16x32_bf16(a1, b1, acc[1][1], 0, 0, 0);
    acc[1][2] = __builtin_amdgcn_mfma_f32_16x16x32_bf16(a1, b2, acc[1][2], 0, 0, 0);
  }

  // LDS transpose: red[w][col_local*33 + row_local]
  __shared__ float red[4 * 48 * 33];
  float* rw = red + w * (48 * 33);
#pragma unroll
  for (int i = 0; i < 2; ++i)
#pragma unroll
    for (int j = 0; j < 3; ++j)
#pragma unroll
      for (int r = 0; r < 4; ++r)
        rw[(j * 16 + c16) * 33 + (i * 16 + quad * 4 + r)] = acc[i][j][r];
  __syncthreads();
  if (lane < 32) {
    float sum = 0.f;
#pragma unroll
    for (int grp = 0; grp < 4; ++grp) {
      float mx = rw[(grp * 12) * 33 + lane];
#pragma unroll
      for (int m = 1; m < 12; ++m)
        mx = fmaxf(mx, rw[(grp * 12 + m) * 33 + lane]);
      sum += mx;
    }
    atomicAdd(&S[bm + lane], sum * (1.0f / 12.0f));
  }
}

// mu/rstd per sample from colsums + S: one wave per n
__global__ __launch_bounds__(64) void ln1_finish(
    const float* __restrict__ S, const float* __restrict__ cxp,
    const float* __restrict__ cx2p, float* __restrict__ smu,
    float* __restrict__ srstd) {
  const int n = blockIdx.x, lane = threadIdx.x;
  float sum = 0.f, sq = 0.f;
  if (lane < 48) {
    float a = 1.0f + S[n * 48 + lane];
    float c1 = 0.f, c2 = 0.f;
#pragma unroll
    for (int ch = 0; ch < 4; ++ch) {
      c1 += cxp[((size_t)n * 4 + ch) * 48 + lane];
      c2 += cx2p[((size_t)n * 4 + ch) * 48 + lane];
    }
    sum = a * c1;
    sq = a * a * c2;
  }
#pragma unroll
  for (int off = 32; off > 0; off >>= 1) {
    sum += __shfl_down(sum, off, 64);
    sq  += __shfl_down(sq, off, 64);
  }
  if (lane == 0) {
    float mu = sum * (1.0f / LNSZ);
    float var = sq * (1.0f / LNSZ) - mu * mu;
    smu[n] = mu;
    srstd[n] = 1.0f / sqrtf(var + 1e-5f);
  }
}

// y = LN1(x*(1+S)) -> fp32 [c][s] AND bf16 [s][c] (fused transpose)
__global__ __launch_bounds__(256) void ln1_norm_tr(
    const float* __restrict__ x, const float* __restrict__ S,
    const float* __restrict__ smu, const float* __restrict__ srstd,
    const float* __restrict__ g, const float* __restrict__ b,
    float* __restrict__ y, __hip_bfloat16* __restrict__ yb) {
  const int bx = blockIdx.x, n = blockIdx.y, t = threadIdx.x;
  __shared__ float ts[128 * 49];
  __shared__ float sS[HW];
  if (t < HW) sS[t] = 1.0f + S[n * HW + t];
  __syncthreads();
  const float mu = smu[n], rstd = srstd[n];
  const size_t chunk = (size_t)bx * 6144;
  const float* xn = x + (size_t)n * LNSZ + chunk;
  float* yn = y + (size_t)n * LNSZ + chunk;
  const float* gp = g + chunk;
  const float* bp = b + chunk;
#pragma unroll
  for (int k = 0; k < 6; ++k) {
    int idx = t + k * 256;
    int c = idx / 12, sq0 = (idx % 12) * 4;
    float4 xv = ((const float4*)xn)[idx];
    float4 gv = ((const float4*)gp)[idx];
    float4 bv = ((const float4*)bp)[idx];
    float4 o;
    o.x = (xv.x * sS[sq0]     - mu) * rstd * gv.x + bv.x;
    o.y = (xv.y * sS[sq0 + 1] - mu) * rstd * gv.y + bv.y;
    o.z = (xv.z * sS[sq0 + 2] - mu) * rstd * gv.z + bv.z;
    o.w = (xv.w * sS[sq0 + 3] - mu) * rstd * gv.w + bv.w;
    ((float4*)yn)[idx] = o;
    float* d = ts + c * 49 + sq0;
    d[0] = o.x; d[1] = o.y; d[2] = o.z; d[3] = o.w;
  }
  __syncthreads();
  __hip_bfloat16* dst = yb + (size_t)n * LNSZ + bx * 128;
#pragma unroll
  for (int k = 0; k < 12; ++k) {
    int idx = t + k * 256;
    int s = idx >> 6, cp = idx & 63;
    __hip_bfloat162 p;
    p.x = __float2bfloat16(ts[(cp * 2) * 49 + s]);
    p.y = __float2bfloat16(ts[(cp * 2 + 1) * 49 + s]);
    *(__hip_bfloat162*)(dst + (size_t)s * 512 + cp * 2) = p;
  }
}

// conv2 with fused residual + LN2 stats: v = y + Wc2@ub; stats2[n][oc]={S,S2}
__global__ __launch_bounds__(256) void conv2_fused(
    const __hip_bfloat16* __restrict__ Wb, const __hip_bfloat16* __restrict__ inb,
    const float* __restrict__ y, float* __restrict__ v,
    float2* __restrict__ stats2) {
  const int oc = blockIdx.x, n = blockIdx.y;
  const int w = threadIdx.x >> 6, lane = threadIdx.x & 63;
  const int c16 = lane & 15, quad = lane >> 4;
  const int obase = oc * 128 + w * 32;

  const __hip_bfloat16* A0 = Wb + (size_t)(obase + c16) * 512 + quad * 8;
  const __hip_bfloat16* A1 = A0 + 16 * 512;
  const __hip_bfloat16* B0 = inb + (size_t)n * LNSZ + (size_t)c16 * 512 + quad * 8;

  floatx4 zero = {0.f, 0.f, 0.f, 0.f};
  floatx4 acc[2][3];
#pragma unroll
  for (int i = 0; i < 2; ++i)
#pragma unroll
    for (int j = 0; j < 3; ++j) acc[i][j] = zero;

  bf16x8 a[2], b[3];
  a[0] = *(const bf16x8*)(A0);
  a[1] = *(const bf16x8*)(A1);
  b[0] = *(const bf16x8*)(B0);
  b[1] = *(const bf16x8*)(B0 + 16 * 512);
  b[2] = *(const bf16x8*)(B0 + 32 * 512);

  for (int k = 0; k < 480; k += 32) {
    bf16x8 an[2], bn[3];
    const int k2 = k + 32;
    an[0] = *(const bf16x8*)(A0 + k2);
    an[1] = *(const bf16x8*)(A1 + k2);
    bn[0] = *(const bf16x8*)(B0 + k2);
    bn[1] = *(const bf16x8*)(B0 + 16 * 512 + k2);
    bn[2] = *(const bf16x8*)(B0 + 32 * 512 + k2);
#pragma unroll
    for (int i = 0; i < 2; ++i)
#pragma unroll
      for (int j = 0; j < 3; ++j)
        acc[i][j] = __builtin_amdgcn_mfma_f32_16x16x32_bf16(a[i], b[j],
                                                            acc[i][j], 0, 0, 0);
    a[0] = an[0]; a[1] = an[1];
    b[0] = bn[0]; b[1] = bn[1]; b[2] = bn[2];
  }
#pragma unroll
  for (int i = 0; i < 2; ++i)
#pragma unroll
    for (int j = 0; j < 3; ++j)
      acc[i][j] = __builtin_amdgcn_mfma_f32_16x16x32_bf16(a[i], b[j],
                                                          acc[i][j], 0, 0, 0);

  const float* yn = y + (size_t)n * LNSZ;
  float* vn = v + (size_t)n * LNSZ;
  float sum = 0.f, sq = 0.f;
#pragma unroll
  for (int i = 0; i < 2; ++i)
#pragma unroll
    for (int r = 0; r < 4; ++r) {
      const int o = obase + i * 16 + quad * 4 + r;
#pragma unroll
      for (int j = 0; j < 3; ++j) {
        const int s = j * 16 + c16;
        float val = acc[i][j][r] + yn[(size_t)o * HW + s];
        vn[(size_t)o * HW + s] = val;
        sum += val;
        sq += val * val;
      }
    }
  block_reduce2(sum, sq);
  if (threadIdx.x == 0) stats2[n * 4 + oc] = make_float2(sum, sq);
}

__global__ __launch_bounds__(256) void ln2_norm(
    const float* __restrict__ v, const float2* __restrict__ stats2,
    const float* __restrict__ g2, const float* __restrict__ b2,
    float* __restrict__ out) {
  const int bx = blockIdx.x, n = blockIdx.y, t = threadIdx.x;
  __shared__ float smu, srstd;
  if (t == 0) {
    float s1 = 0.f, s2 = 0.f;
#pragma unroll
    for (int k = 0; k < 4; ++k) {
      float2 p = stats2[n * 4 + k];
      s1 += p.x; s2 += p.y;
    }
    float mu = s1 * (1.0f / LNSZ);
    float var = s2 * (1.0f / LNSZ) - mu * mu;
    smu = mu;
    srstd = 1.0f / sqrtf(var + 1e-5f);
  }
  __syncthreads();
  const float mu = smu, rstd = srstd;
  const size_t chunk = (size_t)bx * 6144;
  const float* vn = v + (size_t)n * LNSZ + chunk;
  float* on = out + (size_t)n * LNSZ + chunk;
  const float* gp = g2 + chunk;
  const float* bp = b2 + chunk;
#pragma unroll
  for (int k = 0; k < 6; ++k) {
    int idx = t + k * 256;
    float4 vv = ((const float4*)vn)[idx];
    float4 gv = ((const float4*)gp)[idx];
    float4 bv = ((const float4*)bp)[idx];
    float4 o;
    o.x = (vv.x - mu) * rstd * gv.x + bv.x;
    o.y = (vv.y - mu) * rstd * gv.y + bv.y;
    o.z = (vv.z - mu) * rstd * gv.z + bv.z;
    o.w = (vv.w - mu) * rstd * gv.w + bv.w;
    ((float4*)on)[idx] = o;
  }
}

extern "C" void kernel_launch(void* const* d_in, const int* in_sizes, int n_in,
                              void* d_out, int out_size, void* d_ws, size_t ws_size,
                              hipStream_t stream) {
  const float* x   = (const float*)d_in[0];
  const float* tw  = (const float*)d_in[1];
  const float* tb  = (const float*)d_in[2];
  const float* pw  = (const float*)d_in[3];
  const float* pb  = (const float*)d_in[4];
  const float* c1w = (const float*)d_in[5];
  const float* c2w = (const float*)d_in[6];
  const float* g1  = (const float*)d_in[7];
  const float* b1  = (const float*)d_in[8];
  const float* g2  = (const float*)d_in[9];
  const float* b2  = (const float*)d_in[10];

  float* ws = (float*)d_ws;
  __hip_bfloat16* Wb = (__hip_bfloat16*)(ws + WB_OFF);
  float* bcat        = ws + BC_OFF;
  float* S           = ws + S_OFF;
  float* smu         = ws + SMU_OFF;
  float* srstd       = ws + SRS_OFF;
  float* cxp         = ws + CXP_OFF;
  float* cx2p        = ws + CX2_OFF;
  float2* st2        = (float2*)(ws + ST2_OFF);
  __hip_bfloat16* xb = (__hip_bfloat16*)(ws + XB_OFF);
  __hip_bfloat16* tp = (__hip_bfloat16*)(ws + TP_OFF);
  __hip_bfloat16* yb = (__hip_bfloat16*)(ws + YB_OFF);
  __hip_bfloat16* ub = (__hip_bfloat16*)(ws + UB_OFF);
  __hip_bfloat16* Pp = (__hip_bfloat16*)(ws + PP_OFF);
  float* y           = ws + YY_OFF;
  float* v           = ws + VV_OFF;
  float* out         = (float*)d_out;

  // pack weights/biases, zero S
  prep_w<<<3072, 256, 0, stream>>>(tw, pw, c1w, c2w, tb, pb, Wb, bcat, S);
  // x -> bf16 [s][c] + LN1 column stats
  trx_stats<<<dim3(4, NN), 256, 0, stream>>>(x, xb, cxp, cx2p);
  // theta+phi projection, bias fused, transposed bf16 out (== Th ++ phi)
  gemm_bf16out<<<dim3(4, NN), 256, 0, stream>>>(Wb, xb, bcat, tp, 0);
  make_pp<<<768, 256, 0, stream>>>(tp, Pp);
  // score GEMM + pool-max + query-sum -> S (atomic)
  dgemm_fused<<<dim3(16, 24), 256, 0, stream>>>(tp, Pp, S);
  // LN1 mu/rstd from colsums + S
  ln1_finish<<<NN, 64, 0, stream>>>(S, cxp, cx2p, smu, srstd);
  // LN1 apply -> y fp32 + yb bf16 (fused transpose)
  ln1_norm_tr<<<dim3(4, NN), 256, 0, stream>>>(x, S, smu, srstd, g1, b1, y, yb);
  // conv1 + relu -> ub bf16 [s][c]
  gemm_bf16out<<<dim3(4, NN), 256, 0, stream>>>(Wb + 512 * 512, yb, nullptr, ub, 1);
  // conv2 + residual + LN2 stats
  conv2_fused<<<dim3(4, NN), 256, 0, stream>>>(Wb + 1024 * 512, ub, y, v, st2);
  ln2_norm<<<dim3(4, NN), 256, 0, stream>>>(v, st2, g2, b2, out);
}